// Round 1
// baseline (478.045 us; speedup 1.0000x reference)
//
#include <hip/hip_runtime.h>
#include <hip/hip_bf16.h>
#include <math.h>

typedef unsigned short u16;
typedef float f32x4 __attribute__((ext_vector_type(4)));
typedef __bf16 bf16x8 __attribute__((ext_vector_type(8)));

__device__ __forceinline__ float bf2f(u16 u) {
    union { float f; unsigned int i; } v; v.i = ((unsigned int)u) << 16; return v.f;
}
__device__ __forceinline__ u16 f2bf(float f) {
    union { float f; unsigned int i; } v; v.f = f;
    unsigned int x = v.i;
    return (u16)((x + 0x7FFFu + ((x >> 16) & 1u)) >> 16);
}

// ---------------- K0: one-time weight conversion + fragment reordering ----------------
// bid [0,192): wqkvb[768][256] row-major bf16.
// bid [192,320): w1p fragment order [kc16][wave4][ks8][lane64][8]  (up B-frag: n=kc*64+wave*16+ln, k=ks*32+quad*8)
// bid [320,448): w2p fragment order [kc16][wave4][ks2_2][nt4][lane64][8] (down B-frag: n=wave*64+nt*16+ln, k=kc*64+ks2*32+quad*8)
__global__ __launch_bounds__(256) void k_prep(const float* __restrict__ wq, const float* __restrict__ wkv,
                                              const float* __restrict__ w1, const float* __restrict__ w2,
                                              u16* __restrict__ wqkvb, u16* __restrict__ w1p, u16* __restrict__ w2p) {
    const int bid = blockIdx.x, t = threadIdx.x;
    if (bid < 192) {
        int e = (bid * 256 + t) * 4;
        const float* src = (e < 65536) ? (wq + e) : (wkv + (e - 65536));
        float4 v = *(const float4*)src;
        ushort4 o;
        o.x = f2bf(v.x); o.y = f2bf(v.y); o.z = f2bf(v.z); o.w = f2bf(v.w);
        *(ushort4*)(wqkvb + e) = o;
    } else if (bid < 320) {
        int tid = (bid - 192) * 256 + t;
        int kc = tid >> 11, rem = tid & 2047;
        int wave = rem >> 9, rem2 = rem & 511;
        int ks = rem2 >> 6, lane = rem2 & 63;
        int ln = lane & 15, quad = lane >> 4;
        const float* src = w1 + (size_t)(kc * 64 + wave * 16 + ln) * 256 + ks * 32 + quad * 8;
        float4 v0 = *(const float4*)src;
        float4 v1 = *(const float4*)(src + 4);
        alignas(16) u16 tmp[8];
        tmp[0] = f2bf(v0.x); tmp[1] = f2bf(v0.y); tmp[2] = f2bf(v0.z); tmp[3] = f2bf(v0.w);
        tmp[4] = f2bf(v1.x); tmp[5] = f2bf(v1.y); tmp[6] = f2bf(v1.z); tmp[7] = f2bf(v1.w);
        *(int4*)(w1p + (size_t)tid * 8) = *(int4*)tmp;
    } else {
        int tid = (bid - 320) * 256 + t;
        int kc = tid >> 11, rem = tid & 2047;
        int wave = rem >> 9, rem2 = rem & 511;
        int ks2 = rem2 >> 8, rem3 = rem2 & 255;
        int nt = rem3 >> 6, lane = rem3 & 63;
        int ln = lane & 15, quad = lane >> 4;
        const float* src = w2 + (size_t)(wave * 64 + nt * 16 + ln) * 1024 + kc * 64 + ks2 * 32 + quad * 8;
        float4 v0 = *(const float4*)src;
        float4 v1 = *(const float4*)(src + 4);
        alignas(16) u16 tmp[8];
        tmp[0] = f2bf(v0.x); tmp[1] = f2bf(v0.y); tmp[2] = f2bf(v0.z); tmp[3] = f2bf(v0.w);
        tmp[4] = f2bf(v1.x); tmp[5] = f2bf(v1.y); tmp[6] = f2bf(v1.z); tmp[7] = f2bf(v1.w);
        *(int4*)(w2p + (size_t)tid * 8) = *(int4*)tmp;
    }
}

// ---------------- K1: NCHW f32 -> NHWC bf16 transpose ----------------
__global__ __launch_bounds__(256) void k_transpose(const float* __restrict__ x, u16* __restrict__ xh) {
    __shared__ __align__(16) u16 tile[64][72];
    const int t = threadIdx.x;
    const int hw0 = blockIdx.x * 64;
    const int c0  = blockIdx.y * 64;
    const int b   = blockIdx.z;
    const int cl = t >> 2, wl = (t & 3) * 16;
    {
        int c = c0 + cl;
        const float* src = x + (size_t)(b * 256 + c) * 3136 + hw0 + wl;
        for (int q = 0; q < 4; q++) {
            float4 v = *(const float4*)(src + q * 4);
            u16* dst = &tile[cl][wl + q * 4];
            dst[0] = f2bf(v.x); dst[1] = f2bf(v.y); dst[2] = f2bf(v.z); dst[3] = f2bf(v.w);
        }
    }
    __syncthreads();
    const int hl = t >> 3, cl2 = (t & 7) * 8;
    for (int i = 0; i < 2; i++) {
        int hw = hl + i * 32;
        alignas(16) u16 tmp[8];
        for (int j = 0; j < 8; j++) tmp[j] = tile[cl2 + j][hw];
        u16* dst = xh + (size_t)(b * 3136 + hw0 + hw) * 256 + c0 + cl2;
        *(int4*)dst = *(int4*)tmp;
    }
}

// ---------------- K_ln: full LayerNorm, bf16 in -> bf16 out (materialized) ----------------
// grid 12544, block 256 (4 waves, 1 position/wave)
__global__ __launch_bounds__(256) void k_ln(const u16* __restrict__ in, u16* __restrict__ out,
                                            const float* __restrict__ g, const float* __restrict__ bta) {
    const int wave = threadIdx.x >> 6, lane = threadIdx.x & 63;
    const int p = blockIdx.x * 4 + wave;
    ushort4 v = *(const ushort4*)(in + (size_t)p * 256 + lane * 4);
    float f0 = bf2f(v.x), f1 = bf2f(v.y), f2 = bf2f(v.z), f3 = bf2f(v.w);
    float s = f0 + f1 + f2 + f3;
    float sq = f0 * f0 + f1 * f1 + f2 * f2 + f3 * f3;
    for (int o = 32; o >= 1; o >>= 1) { s += __shfl_xor(s, o, 64); sq += __shfl_xor(sq, o, 64); }
    float m = s * (1.f / 256.f);
    float var = sq * (1.f / 256.f) - m * m;
    float inv = rsqrtf(var + 1e-5f);
    float4 gv = *(const float4*)(g + lane * 4);
    float4 bv = *(const float4*)(bta + lane * 4);
    ushort4 o4;
    o4.x = f2bf((f0 - m) * inv * gv.x + bv.x);
    o4.y = f2bf((f1 - m) * inv * gv.y + bv.y);
    o4.z = f2bf((f2 - m) * inv * gv.z + bv.z);
    o4.w = f2bf((f3 - m) * inv * gv.w + bv.w);
    *(ushort4*)(out + (size_t)p * 256 + lane * 4) = o4;
}

// ---------------- K_qkv: qkv = xn @ wqkvb^T + [bq;bkv]  (pure-copy staging) ----------------
// grid 2352 1D, XCD-swizzled.
__global__ __launch_bounds__(256) void k_qkv(
    const u16* __restrict__ xn, const u16* __restrict__ Bw,
    const float* __restrict__ bq, const float* __restrict__ bkv,
    u16* __restrict__ out) {
    __shared__ __align__(16) u16 smem[17408];
    u16* As = smem;          // 128*32
    u16* Bs = smem + 4096;   // 128*32

    const int g = blockIdx.x;
    const int xcd = g & 7, idx = g >> 3;
    const int bm = xcd * 49 + idx / 6, bn = idx % 6;

    const int t = threadIdx.x;
    const int wave = t >> 6, lane = t & 63;
    const int wm = (wave >> 1) * 64, wn = (wave & 1) * 64;
    const int ln = lane & 15, quad = lane >> 4;

    f32x4 vzero = {0.f, 0.f, 0.f, 0.f};
    f32x4 acc[4][4];
    for (int i = 0; i < 4; i++) for (int j = 0; j < 4; j++) acc[i][j] = vzero;

    const int srow = t >> 2;
    const int scol = (t & 3) * 8;

    for (int k0 = 0; k0 < 256; k0 += 32) {
        for (int i = 0; i < 2; i++) {
            int r = srow + i * 64;
            *(int4*)&As[r * 32 + scol] = *(const int4*)(xn + (size_t)(bm * 128 + r) * 256 + k0 + scol);
            *(int4*)&Bs[r * 32 + scol] = *(const int4*)(Bw + (size_t)(bn * 128 + r) * 256 + k0 + scol);
        }
        __syncthreads();
        bf16x8 af[4], bfr[4];
        for (int mt = 0; mt < 4; mt++) af[mt] = *(const bf16x8*)&As[(wm + mt * 16 + ln) * 32 + quad * 8];
        for (int nt = 0; nt < 4; nt++) bfr[nt] = *(const bf16x8*)&Bs[(wn + nt * 16 + ln) * 32 + quad * 8];
        for (int mt = 0; mt < 4; mt++)
            for (int nt = 0; nt < 4; nt++)   // swapped: lane owns row (m), 4 consecutive cols
                acc[mt][nt] = __builtin_amdgcn_mfma_f32_16x16x32_bf16(bfr[nt], af[mt], acc[mt][nt], 0, 0, 0);
        __syncthreads();
    }

    u16* Cs = smem;  // [128][136]
    for (int nt = 0; nt < 4; nt++) {
        int gn0 = bn * 128 + wn + nt * 16 + quad * 4;
        f32x4 bv = (gn0 < 256) ? *(const f32x4*)(bq + gn0) : *(const f32x4*)(bkv + gn0 - 256);
        for (int mt = 0; mt < 4; mt++) {
            ushort4 pk;
            pk.x = f2bf(acc[mt][nt][0] + bv[0]);
            pk.y = f2bf(acc[mt][nt][1] + bv[1]);
            pk.z = f2bf(acc[mt][nt][2] + bv[2]);
            pk.w = f2bf(acc[mt][nt][3] + bv[3]);
            *(ushort4*)&Cs[(wm + mt * 16 + ln) * 136 + wn + nt * 16 + quad * 4] = pk;
        }
    }
    __syncthreads();
    const int row = t >> 4, col = (t & 15) * 8;
    for (int pass = 0; pass < 8; pass++) {
        int rr = pass * 16 + row;
        int4 v = *(int4*)&Cs[rr * 136 + col];
        *(int4*)(out + (size_t)(bm * 128 + rr) * 768 + bn * 128 + col) = v;
    }
}

// ---------------- K_mlp: fused out = x2 + g2*(gelu(xn@w1^T+b1)@w2^T+b2), NCHW f32 ----------------
// grid 784 XCD-swizzled; block = 64 positions.
// v2 structure: 8 H-chunks of 128 (was 16 of 64).
//  - up: wave owns 64m x 32n slice; swapped-operand MFMA so lane owns m row ->
//    packed ushort4 H writes (was 16 scalar b16 writes/chunk).
//  - A-tile fragments re-read half as often (each af feeds 2 MFMAs).
//  - Hs single-buffered 64x136 (17.4KB); As 64x264 (33.8KB); 51.2KB -> 3 blocks/CU.
//  - w1p/w2p layouts unchanged; only group-index remap:
//      w1: n=kc*128+wave*32+nt*16+ln -> group kc*8+(wave>>1)*4+(wave&1)*2+nt
//      w2: k=kc*128+ks2*32+quad*8    -> kcO=kc*2+(ks2>>1), ks2O=ks2&1
__global__ __launch_bounds__(256, 3) void k_mlp(
    const u16* __restrict__ xn, const u16* __restrict__ x2,
    const u16* __restrict__ w1p, const float* __restrict__ b1,
    const u16* __restrict__ w2p, const float* __restrict__ b2,
    const float* __restrict__ g2v, float* __restrict__ outT) {
    __shared__ __align__(16) u16 smem[16896 + 8704];  // As 64x264, Hs 64x136
    u16* As = smem;
    u16* Hs = smem + 16896;

    const int g = blockIdx.x;
    const int bm = (g & 7) * 98 + (g >> 3);

    const int t = threadIdx.x;
    const int wave = t >> 6, lane = t & 63;
    const int ln = lane & 15, quad = lane >> 4;
    const int wn64 = wave * 64;
    const int wq4 = (wave >> 1) * 4 + (wave & 1) * 2;   // w1 group base for this wave

    f32x4 vzero = {0.f, 0.f, 0.f, 0.f};
    f32x4 acc[4][4];  // [mt][nt]: n = wn64+nt*16+ln, m = mt*16+quad*4+r
    for (int i = 0; i < 4; i++) for (int j = 0; j < 4; j++) acc[i][j] = vzero;

    // stage A tile (pure copy, already LN'd)
    {
        const int srow = t >> 2, scb = (t & 3) * 8;
        for (int c = 0; c < 8; c++) {
            int col = scb + c * 32;
            *(int4*)&As[srow * 264 + col] = *(const int4*)(xn + (size_t)(bm * 64 + srow) * 256 + col);
        }
    }
    __syncthreads();

    for (int kc = 0; kc < 8; kc++) {
        // ---- up: H chunk 64m x 128n; this wave computes 64m x 32n (nt=0,1). ----
        f32x4 up[4][2];
        #pragma unroll
        for (int i = 0; i < 4; i++) { up[i][0] = vzero; up[i][1] = vzero; }
        const u16* w1b = w1p + (size_t)(kc * 8 + wq4) * 4096 + lane * 8;  // +nt*4096, +ks*512
        #pragma unroll
        for (int ks = 0; ks < 8; ks++) {
            bf16x8 w10 = *(const bf16x8*)(w1b + ks * 512);
            bf16x8 w11 = *(const bf16x8*)(w1b + 4096 + ks * 512);
            #pragma unroll
            for (int mt = 0; mt < 4; mt++) {
                bf16x8 af = *(const bf16x8*)&As[(mt * 16 + ln) * 264 + ks * 32 + quad * 8];
                // swapped operands: lane owns m = mt*16+ln; regs r are n = nt*16+quad*4+r
                up[mt][0] = __builtin_amdgcn_mfma_f32_16x16x32_bf16(w10, af, up[mt][0], 0, 0, 0);
                up[mt][1] = __builtin_amdgcn_mfma_f32_16x16x32_bf16(w11, af, up[mt][1], 0, 0, 0);
            }
        }
        // gelu (sigmoid form; downstream scaled by gamma2~1e-6) -> packed b64 writes
        #pragma unroll
        for (int nt = 0; nt < 2; nt++) {
            float4 bv = *(const float4*)(b1 + kc * 128 + wave * 32 + nt * 16 + quad * 4);
            #pragma unroll
            for (int mt = 0; mt < 4; mt++) {
                float v0 = up[mt][nt][0] + bv.x;
                float v1 = up[mt][nt][1] + bv.y;
                float v2 = up[mt][nt][2] + bv.z;
                float v3 = up[mt][nt][3] + bv.w;
                ushort4 pk;
                pk.x = f2bf(v0 * (1.f / (1.f + __expf(-1.702f * v0))));
                pk.y = f2bf(v1 * (1.f / (1.f + __expf(-1.702f * v1))));
                pk.z = f2bf(v2 * (1.f / (1.f + __expf(-1.702f * v2))));
                pk.w = f2bf(v3 * (1.f / (1.f + __expf(-1.702f * v3))));
                *(ushort4*)&Hs[(mt * 16 + ln) * 136 + wave * 32 + nt * 16 + quad * 4] = pk;
            }
        }
        __syncthreads();
        // ---- down: acc += H(64x128) @ W2chunk^T; K=128 in 4 slices of 32. ----
        #pragma unroll
        for (int ks2 = 0; ks2 < 4; ks2++) {
            bf16x8 hf[4];
            #pragma unroll
            for (int mt = 0; mt < 4; mt++)
                hf[mt] = *(const bf16x8*)&Hs[(mt * 16 + ln) * 136 + ks2 * 32 + quad * 8];
            const u16* w2b = w2p + (size_t)((((kc * 2 + (ks2 >> 1)) * 4 + wave) * 2 + (ks2 & 1)) * 4) * 512 + lane * 8;
            #pragma unroll
            for (int nt = 0; nt < 4; nt++) {
                bf16x8 w2f = *(const bf16x8*)(w2b + nt * 512);
                #pragma unroll
                for (int mt = 0; mt < 4; mt++)
                    acc[mt][nt] = __builtin_amdgcn_mfma_f32_16x16x32_bf16(hf[mt], w2f, acc[mt][nt], 0, 0, 0);
            }
        }
        __syncthreads();  // Hs reused next chunk
    }

    // epilogue: lane owns channel gn, 4 consecutive positions -> float4 NCHW store
    const int b = bm / 49;
    for (int nt = 0; nt < 4; nt++) {
        int gn = wn64 + nt * 16 + ln;
        float bs = b2[gn], g2 = g2v[gn];
        for (int mt = 0; mt < 4; mt++) {
            int gm0 = bm * 64 + mt * 16 + quad * 4;
            int hw0 = gm0 - b * 3136;
            f32x4 res;
            for (int r = 0; r < 4; r++)
                res[r] = bf2f(x2[(size_t)(gm0 + r) * 256 + gn]) + g2 * (acc[mt][nt][r] + bs);
            *(f32x4*)(outT + (size_t)(b * 256 + gn) * 3136 + hw0) = res;
        }
    }
}

// ---------------- K_attn: halo attention + LayerScale residual ----------------
__global__ __launch_bounds__(256) void k_attn(
    const u16* __restrict__ qkv, const float* __restrict__ bias,
    const u16* __restrict__ xh, const float* __restrict__ gamma1,
    u16* __restrict__ x2) {
    __shared__ __align__(16) u16 Kl[208 * 40];
    __shared__ __align__(16) u16 Vt[32 * 232];
    __shared__ __align__(16) u16 Pl[4][16 * 232];

    const int t = threadIdx.x;
    const int blk = blockIdx.x, head = blockIdx.y, b = blockIdx.z;
    const int bh = blk / 7, bw = blk - bh * 7;
    const int wave = t >> 6, lane = t & 63;
    const int ln = lane & 15, quad = lane >> 4;

    {
        int4 z = {0, 0, 0, 0};
        for (int i = t; i < (32 * 232) / 8; i += 256) ((int4*)Vt)[i] = z;
        for (int i = t; i < (4 * 16 * 232) / 8; i += 256) ((int4*)&Pl[0][0])[i] = z;
    }
    __syncthreads();

    for (int cid = t; cid < 208 * 8; cid += 256) {
        int pos = cid >> 3, part = cid & 7;
        int i = pos / 14, j = pos - i * 14;
        int gh = bh * 8 - 3 + i, gw = bw * 8 - 3 + j;
        bool valid = (pos < 196) && ((unsigned)gh < 56u) && ((unsigned)gw < 56u);
        int d0 = (part & 3) * 8;
        int4 v = {0, 0, 0, 0};
        if (valid) {
            size_t p = (size_t)(b * 56 + gh) * 56 + gw;
            v = *(const int4*)(qkv + p * 768 + 256 + head * 64 + ((part & 4) ? 32 : 0) + d0);
        }
        if (!(part & 4)) {
            *(int4*)&Kl[pos * 40 + d0] = v;
        } else {
            alignas(16) u16 tmp[8];
            *(int4*)tmp = v;
            for (int jj = 0; jj < 8; jj++) Vt[(d0 + jj) * 232 + pos] = tmp[jj];
        }
    }
    __syncthreads();

    const int qrow = wave * 16 + ln;
    const int qh = bh * 8 + (qrow >> 3), qw = bw * 8 + (qrow & 7);
    const size_t qp = (size_t)(b * 56 + qh) * 56 + qw;
    bf16x8 qf = *(const bf16x8*)(qkv + qp * 768 + head * 32 + quad * 8);

    f32x4 vzero = {0.f, 0.f, 0.f, 0.f};
    float sv[13][4];
    float mx[4] = {-1e30f, -1e30f, -1e30f, -1e30f};
    const float scale = 0.17677669529663687f;
    for (int nt = 0; nt < 13; nt++) {
        bf16x8 kf = *(const bf16x8*)&Kl[(nt * 16 + ln) * 40 + quad * 8];
        f32x4 s = __builtin_amdgcn_mfma_f32_16x16x32_bf16(qf, kf, vzero, 0, 0, 0);
        int kk = nt * 16 + ln;
        bool kvalid = kk < 196;
        for (int r = 0; r < 4; r++) {
            int qq = wave * 16 + quad * 4 + r;
            float val = kvalid ? (s[r] * scale + bias[(size_t)(head * 64 + qq) * 196 + kk]) : -1e30f;
            sv[nt][r] = val;
            mx[r] = fmaxf(mx[r], val);
        }
    }
    for (int o = 1; o < 16; o <<= 1)
        for (int r = 0; r < 4; r++) mx[r] = fmaxf(mx[r], __shfl_xor(mx[r], o, 16));
    float sum[4] = {0.f, 0.f, 0.f, 0.f};
    for (int nt = 0; nt < 13; nt++)
        for (int r = 0; r < 4; r++) {
            float e = __expf(sv[nt][r] - mx[r]);
            sv[nt][r] = e;
            sum[r] += e;
        }
    for (int o = 1; o < 16; o <<= 1)
        for (int r = 0; r < 4; r++) sum[r] += __shfl_xor(sum[r], o, 16);
    float rinv[4];
    for (int r = 0; r < 4; r++) rinv[r] = 1.f / sum[r];

    u16* plw = &Pl[wave][0];
    for (int nt = 0; nt < 13; nt++)
        for (int r = 0; r < 4; r++)
            plw[(quad * 4 + r) * 232 + nt * 16 + ln] = f2bf(sv[nt][r]);
    __syncthreads();

    f32x4 o_acc[2];
    o_acc[0] = vzero; o_acc[1] = vzero;
    for (int kc = 0; kc < 7; kc++) {
        bf16x8 pf = *(const bf16x8*)&plw[ln * 232 + kc * 32 + quad * 8];
        for (int n2 = 0; n2 < 2; n2++) {
            bf16x8 vf = *(const bf16x8*)&Vt[(n2 * 16 + ln) * 232 + kc * 32 + quad * 8];
            o_acc[n2] = __builtin_amdgcn_mfma_f32_16x16x32_bf16(pf, vf, o_acc[n2], 0, 0, 0);
        }
    }

    for (int n2 = 0; n2 < 2; n2++) {
        int c = head * 32 + n2 * 16 + ln;
        float g1 = gamma1[c];
        for (int r = 0; r < 4; r++) {
            int q = wave * 16 + quad * 4 + r;
            int hh = bh * 8 + (q >> 3), ww = bw * 8 + (q & 7);
            size_t p = (size_t)(b * 56 + hh) * 56 + ww;
            float a = o_acc[n2][r] * rinv[r];
            x2[p * 256 + c] = f2bf(bf2f(xh[p * 256 + c]) + g1 * a);
        }
    }
}

extern "C" void kernel_launch(void* const* d_in, const int* in_sizes, int n_in,
                              void* d_out, int out_size, void* d_ws, size_t ws_size,
                              hipStream_t stream) {
    const float* x      = (const float*)d_in[0];
    const float* ln1_g  = (const float*)d_in[1];
    const float* ln1_b  = (const float*)d_in[2];
    const float* wq     = (const float*)d_in[3];
    const float* bq     = (const float*)d_in[4];
    const float* wkv    = (const float*)d_in[5];
    const float* bkv    = (const float*)d_in[6];
    const float* bias   = (const float*)d_in[7];
    const float* gamma1 = (const float*)d_in[8];
    const float* ln2_g  = (const float*)d_in[9];
    const float* ln2_b  = (const float*)d_in[10];
    const float* w1     = (const float*)d_in[11];
    const float* b1     = (const float*)d_in[12];
    const float* w2     = (const float*)d_in[13];
    const float* b2     = (const float*)d_in[14];
    const float* gamma2 = (const float*)d_in[15];

    char* ws = (char*)d_ws;
    u16* qkv   = (u16*)ws;                      // 77,070,336 B
    u16* xh    = (u16*)(ws + 77070336);         // 25,690,112 B  (also reused as xn2)
    u16* x2    = (u16*)(ws + 102760448);        // 25,690,112 B  (also reused as xn1)
    u16* wqkvb = (u16*)(ws + 128450560);        // 393,216 B
    u16* w1p   = (u16*)(ws + 128843776);        // 524,288 B
    u16* w2p   = (u16*)(ws + 129368064);        // 524,288 B
    u16* xn1   = x2;   // LN1 output; dead before k_attn writes x2
    u16* xn2   = xh;   // LN2 output; xh dead after k_attn

    k_prep<<<dim3(448), 256, 0, stream>>>(wq, wkv, w1, w2, wqkvb, w1p, w2p);
    k_transpose<<<dim3(49, 4, 16), 256, 0, stream>>>(x, xh);
    k_ln<<<dim3(12544), 256, 0, stream>>>(xh, xn1, ln1_g, ln1_b);
    k_qkv<<<dim3(2352), 256, 0, stream>>>(xn1, wqkvb, bq, bkv, qkv);
    k_attn<<<dim3(49, 8, 16), 256, 0, stream>>>(qkv, bias, xh, gamma1, x2);
    k_ln<<<dim3(12544), 256, 0, stream>>>(x2, xn2, ln2_g, ln2_b);
    k_mlp<<<dim3(784), 256, 0, stream>>>(xn2, x2, w1p, b1, w2p, b2, gamma2, (float*)d_out);
}

// Round 2
// 393.068 us; speedup vs baseline: 1.2162x; 1.2162x over previous
//
#include <hip/hip_runtime.h>
#include <hip/hip_bf16.h>
#include <math.h>

typedef unsigned short u16;
typedef float f32x4 __attribute__((ext_vector_type(4)));
typedef __bf16 bf16x8 __attribute__((ext_vector_type(8)));

__device__ __forceinline__ float bf2f(u16 u) {
    union { float f; unsigned int i; } v; v.i = ((unsigned int)u) << 16; return v.f;
}
__device__ __forceinline__ u16 f2bf(float f) {
    union { float f; unsigned int i; } v; v.f = f;
    unsigned int x = v.i;
    return (u16)((x + 0x7FFFu + ((x >> 16) & 1u)) >> 16);
}

// ---------------- K0: one-time weight conversion + fragment reordering ----------------
// bid [0,192): wqkvb[768][256] row-major bf16.
// bid [192,320): w1p fragment order [n16 64][ks8][lane64][8]  (up B-frag: n=n16*16+ln, k=ks*32+quad*8)
// bid [320,448): w2p fragment order [kc16][wave4][ks2_2][nt4][lane64][8] (down B-frag: n=wave*64+nt*16+ln, k=kc*64+ks2*32+quad*8)
__global__ __launch_bounds__(256) void k_prep(const float* __restrict__ wq, const float* __restrict__ wkv,
                                              const float* __restrict__ w1, const float* __restrict__ w2,
                                              u16* __restrict__ wqkvb, u16* __restrict__ w1p, u16* __restrict__ w2p) {
    const int bid = blockIdx.x, t = threadIdx.x;
    if (bid < 192) {
        int e = (bid * 256 + t) * 4;
        const float* src = (e < 65536) ? (wq + e) : (wkv + (e - 65536));
        float4 v = *(const float4*)src;
        ushort4 o;
        o.x = f2bf(v.x); o.y = f2bf(v.y); o.z = f2bf(v.z); o.w = f2bf(v.w);
        *(ushort4*)(wqkvb + e) = o;
    } else if (bid < 320) {
        int tid = (bid - 192) * 256 + t;
        int kc = tid >> 11, rem = tid & 2047;
        int wave = rem >> 9, rem2 = rem & 511;
        int ks = rem2 >> 6, lane = rem2 & 63;
        int ln = lane & 15, quad = lane >> 4;
        const float* src = w1 + (size_t)(kc * 64 + wave * 16 + ln) * 256 + ks * 32 + quad * 8;
        float4 v0 = *(const float4*)src;
        float4 v1 = *(const float4*)(src + 4);
        alignas(16) u16 tmp[8];
        tmp[0] = f2bf(v0.x); tmp[1] = f2bf(v0.y); tmp[2] = f2bf(v0.z); tmp[3] = f2bf(v0.w);
        tmp[4] = f2bf(v1.x); tmp[5] = f2bf(v1.y); tmp[6] = f2bf(v1.z); tmp[7] = f2bf(v1.w);
        *(int4*)(w1p + (size_t)tid * 8) = *(int4*)tmp;
    } else {
        int tid = (bid - 320) * 256 + t;
        int kc = tid >> 11, rem = tid & 2047;
        int wave = rem >> 9, rem2 = rem & 511;
        int ks2 = rem2 >> 8, rem3 = rem2 & 255;
        int nt = rem3 >> 6, lane = rem3 & 63;
        int ln = lane & 15, quad = lane >> 4;
        const float* src = w2 + (size_t)(wave * 64 + nt * 16 + ln) * 1024 + kc * 64 + ks2 * 32 + quad * 8;
        float4 v0 = *(const float4*)src;
        float4 v1 = *(const float4*)(src + 4);
        alignas(16) u16 tmp[8];
        tmp[0] = f2bf(v0.x); tmp[1] = f2bf(v0.y); tmp[2] = f2bf(v0.z); tmp[3] = f2bf(v0.w);
        tmp[4] = f2bf(v1.x); tmp[5] = f2bf(v1.y); tmp[6] = f2bf(v1.z); tmp[7] = f2bf(v1.w);
        *(int4*)(w2p + (size_t)tid * 8) = *(int4*)tmp;
    }
}

// ---------------- K1: NCHW f32 -> NHWC bf16 transpose ----------------
__global__ __launch_bounds__(256) void k_transpose(const float* __restrict__ x, u16* __restrict__ xh) {
    __shared__ __align__(16) u16 tile[64][72];
    const int t = threadIdx.x;
    const int hw0 = blockIdx.x * 64;
    const int c0  = blockIdx.y * 64;
    const int b   = blockIdx.z;
    const int cl = t >> 2, wl = (t & 3) * 16;
    {
        int c = c0 + cl;
        const float* src = x + (size_t)(b * 256 + c) * 3136 + hw0 + wl;
        for (int q = 0; q < 4; q++) {
            float4 v = *(const float4*)(src + q * 4);
            u16* dst = &tile[cl][wl + q * 4];
            dst[0] = f2bf(v.x); dst[1] = f2bf(v.y); dst[2] = f2bf(v.z); dst[3] = f2bf(v.w);
        }
    }
    __syncthreads();
    const int hl = t >> 3, cl2 = (t & 7) * 8;
    for (int i = 0; i < 2; i++) {
        int hw = hl + i * 32;
        alignas(16) u16 tmp[8];
        for (int j = 0; j < 8; j++) tmp[j] = tile[cl2 + j][hw];
        u16* dst = xh + (size_t)(b * 3136 + hw0 + hw) * 256 + c0 + cl2;
        *(int4*)dst = *(int4*)tmp;
    }
}

// ---------------- K_ln: full LayerNorm, bf16 in -> bf16 out (materialized) ----------------
// grid 12544, block 256 (4 waves, 1 position/wave)
__global__ __launch_bounds__(256) void k_ln(const u16* __restrict__ in, u16* __restrict__ out,
                                            const float* __restrict__ g, const float* __restrict__ bta) {
    const int wave = threadIdx.x >> 6, lane = threadIdx.x & 63;
    const int p = blockIdx.x * 4 + wave;
    ushort4 v = *(const ushort4*)(in + (size_t)p * 256 + lane * 4);
    float f0 = bf2f(v.x), f1 = bf2f(v.y), f2 = bf2f(v.z), f3 = bf2f(v.w);
    float s = f0 + f1 + f2 + f3;
    float sq = f0 * f0 + f1 * f1 + f2 * f2 + f3 * f3;
    for (int o = 32; o >= 1; o >>= 1) { s += __shfl_xor(s, o, 64); sq += __shfl_xor(sq, o, 64); }
    float m = s * (1.f / 256.f);
    float var = sq * (1.f / 256.f) - m * m;
    float inv = rsqrtf(var + 1e-5f);
    float4 gv = *(const float4*)(g + lane * 4);
    float4 bv = *(const float4*)(bta + lane * 4);
    ushort4 o4;
    o4.x = f2bf((f0 - m) * inv * gv.x + bv.x);
    o4.y = f2bf((f1 - m) * inv * gv.y + bv.y);
    o4.z = f2bf((f2 - m) * inv * gv.z + bv.z);
    o4.w = f2bf((f3 - m) * inv * gv.w + bv.w);
    *(ushort4*)(out + (size_t)p * 256 + lane * 4) = o4;
}

// ---------------- K_qkv: qkv = xn @ wqkvb^T + [bq;bkv]  (pure-copy staging) ----------------
// grid 2352 1D, XCD-swizzled.
__global__ __launch_bounds__(256) void k_qkv(
    const u16* __restrict__ xn, const u16* __restrict__ Bw,
    const float* __restrict__ bq, const float* __restrict__ bkv,
    u16* __restrict__ out) {
    __shared__ __align__(16) u16 smem[17408];
    u16* As = smem;          // 128*32
    u16* Bs = smem + 4096;   // 128*32

    const int g = blockIdx.x;
    const int xcd = g & 7, idx = g >> 3;
    const int bm = xcd * 49 + idx / 6, bn = idx % 6;

    const int t = threadIdx.x;
    const int wave = t >> 6, lane = t & 63;
    const int wm = (wave >> 1) * 64, wn = (wave & 1) * 64;
    const int ln = lane & 15, quad = lane >> 4;

    f32x4 vzero = {0.f, 0.f, 0.f, 0.f};
    f32x4 acc[4][4];
    for (int i = 0; i < 4; i++) for (int j = 0; j < 4; j++) acc[i][j] = vzero;

    const int srow = t >> 2;
    const int scol = (t & 3) * 8;

    for (int k0 = 0; k0 < 256; k0 += 32) {
        for (int i = 0; i < 2; i++) {
            int r = srow + i * 64;
            *(int4*)&As[r * 32 + scol] = *(const int4*)(xn + (size_t)(bm * 128 + r) * 256 + k0 + scol);
            *(int4*)&Bs[r * 32 + scol] = *(const int4*)(Bw + (size_t)(bn * 128 + r) * 256 + k0 + scol);
        }
        __syncthreads();
        bf16x8 af[4], bfr[4];
        for (int mt = 0; mt < 4; mt++) af[mt] = *(const bf16x8*)&As[(wm + mt * 16 + ln) * 32 + quad * 8];
        for (int nt = 0; nt < 4; nt++) bfr[nt] = *(const bf16x8*)&Bs[(wn + nt * 16 + ln) * 32 + quad * 8];
        for (int mt = 0; mt < 4; mt++)
            for (int nt = 0; nt < 4; nt++)   // swapped: lane owns row (m), 4 consecutive cols
                acc[mt][nt] = __builtin_amdgcn_mfma_f32_16x16x32_bf16(bfr[nt], af[mt], acc[mt][nt], 0, 0, 0);
        __syncthreads();
    }

    u16* Cs = smem;  // [128][136]
    for (int nt = 0; nt < 4; nt++) {
        int gn0 = bn * 128 + wn + nt * 16 + quad * 4;
        f32x4 bv = (gn0 < 256) ? *(const f32x4*)(bq + gn0) : *(const f32x4*)(bkv + gn0 - 256);
        for (int mt = 0; mt < 4; mt++) {
            ushort4 pk;
            pk.x = f2bf(acc[mt][nt][0] + bv[0]);
            pk.y = f2bf(acc[mt][nt][1] + bv[1]);
            pk.z = f2bf(acc[mt][nt][2] + bv[2]);
            pk.w = f2bf(acc[mt][nt][3] + bv[3]);
            *(ushort4*)&Cs[(wm + mt * 16 + ln) * 136 + wn + nt * 16 + quad * 4] = pk;
        }
    }
    __syncthreads();
    const int row = t >> 4, col = (t & 15) * 8;
    for (int pass = 0; pass < 8; pass++) {
        int rr = pass * 16 + row;
        int4 v = *(int4*)&Cs[rr * 136 + col];
        *(int4*)(out + (size_t)(bm * 128 + rr) * 768 + bn * 128 + col) = v;
    }
}

// ---------------- K_mlp: fused out = x2 + g2*(gelu(xn@w1^T+b1)@w2^T+b2), NCHW f32 ----------------
// grid 784 XCD-swizzled; block = 64 positions.
// v3 = v2's dataflow (128-wide H chunks, swapped-operand up, packed b64 H writes,
//      halved As re-reads) + v1's schedule (batched register prefetch of ALL
//      w1/w2 fragments per chunk -> one vmcnt wait instead of per-iteration
//      load-use stalls; double-buffered Hs -> single barrier per chunk, a wave
//      may run ahead into the next chunk's independent up phase).
// Safety of 1 barrier/chunk: writes to buffer (kc&1) in chunk kc happen after
// passing barrier(kc-1); all readers of that buffer (down of chunk kc-2) are
// before barrier(kc-1) in program order. Same argument as v1.
// LDS 68608 B -> 2 blocks/CU (regs already limit to ~8 waves/CU anyway).
__global__ __launch_bounds__(256) void k_mlp(
    const u16* __restrict__ xn, const u16* __restrict__ x2,
    const u16* __restrict__ w1p, const float* __restrict__ b1,
    const u16* __restrict__ w2p, const float* __restrict__ b2,
    const float* __restrict__ g2v, float* __restrict__ outT) {
    __shared__ __align__(16) u16 smem[16896 + 2 * 8704];  // As 64x264, Hs[2] 64x136
    u16* As = smem;

    const int g = blockIdx.x;
    const int bm = (g & 7) * 98 + (g >> 3);

    const int t = threadIdx.x;
    const int wave = t >> 6, lane = t & 63;
    const int ln = lane & 15, quad = lane >> 4;
    const int wn64 = wave * 64;
    const int wq4 = (wave >> 1) * 4 + (wave & 1) * 2;   // = wave*2 (w1 group base)

    f32x4 vzero = {0.f, 0.f, 0.f, 0.f};
    f32x4 acc[4][4];  // [mt][nt]: n = wn64+nt*16+ln, m = mt*16+quad*4+r
    for (int i = 0; i < 4; i++) for (int j = 0; j < 4; j++) acc[i][j] = vzero;

    // stage A tile (pure copy, already LN'd)
    {
        const int srow = t >> 2, scb = (t & 3) * 8;
        for (int c = 0; c < 8; c++) {
            int col = scb + c * 32;
            *(int4*)&As[srow * 264 + col] = *(const int4*)(xn + (size_t)(bm * 64 + srow) * 256 + col);
        }
    }
    __syncthreads();

    for (int kc = 0; kc < 8; kc++) {
        u16* Hs = smem + 16896 + (kc & 1) * 8704;  // double-buffered H chunk
        // ---- batch-prefetch all 16 w1 fragments for this chunk ----
        bf16x8 w1f[2][8];
        {
            const u16* w1b = w1p + (size_t)(kc * 8 + wq4) * 4096 + lane * 8;
            #pragma unroll
            for (int nt = 0; nt < 2; nt++)
                #pragma unroll
                for (int ks = 0; ks < 8; ks++)
                    w1f[nt][ks] = *(const bf16x8*)(w1b + nt * 4096 + ks * 512);
        }
        // ---- up: H chunk 64m x 128n; this wave computes 64m x 32n. ----
        f32x4 up[4][2];
        #pragma unroll
        for (int i = 0; i < 4; i++) { up[i][0] = vzero; up[i][1] = vzero; }
        #pragma unroll
        for (int ks = 0; ks < 8; ks++) {
            #pragma unroll
            for (int mt = 0; mt < 4; mt++) {
                bf16x8 af = *(const bf16x8*)&As[(mt * 16 + ln) * 264 + ks * 32 + quad * 8];
                // swapped operands: lane owns m = mt*16+ln; regs r are n = nt*16+quad*4+r
                up[mt][0] = __builtin_amdgcn_mfma_f32_16x16x32_bf16(w1f[0][ks], af, up[mt][0], 0, 0, 0);
                up[mt][1] = __builtin_amdgcn_mfma_f32_16x16x32_bf16(w1f[1][ks], af, up[mt][1], 0, 0, 0);
            }
        }
        // ---- batch-prefetch all 16 w2 fragments (issue before barrier; used after) ----
        bf16x8 w2f[4][4];
        #pragma unroll
        for (int ks2 = 0; ks2 < 4; ks2++) {
            const u16* w2b = w2p + (size_t)((((kc * 2 + (ks2 >> 1)) * 4 + wave) * 2 + (ks2 & 1)) * 4) * 512 + lane * 8;
            #pragma unroll
            for (int nt = 0; nt < 4; nt++)
                w2f[ks2][nt] = *(const bf16x8*)(w2b + nt * 512);
        }
        // ---- gelu (sigmoid form; downstream scaled by gamma2~1e-6) -> packed b64 writes ----
        #pragma unroll
        for (int nt = 0; nt < 2; nt++) {
            float4 bv = *(const float4*)(b1 + kc * 128 + wave * 32 + nt * 16 + quad * 4);
            #pragma unroll
            for (int mt = 0; mt < 4; mt++) {
                float v0 = up[mt][nt][0] + bv.x;
                float v1 = up[mt][nt][1] + bv.y;
                float v2 = up[mt][nt][2] + bv.z;
                float v3 = up[mt][nt][3] + bv.w;
                ushort4 pk;
                pk.x = f2bf(v0 * (1.f / (1.f + __expf(-1.702f * v0))));
                pk.y = f2bf(v1 * (1.f / (1.f + __expf(-1.702f * v1))));
                pk.z = f2bf(v2 * (1.f / (1.f + __expf(-1.702f * v2))));
                pk.w = f2bf(v3 * (1.f / (1.f + __expf(-1.702f * v3))));
                *(ushort4*)&Hs[(mt * 16 + ln) * 136 + wave * 32 + nt * 16 + quad * 4] = pk;
            }
        }
        __syncthreads();
        // ---- down: acc += H(64x128) @ W2chunk^T; K=128 in 4 slices of 32. ----
        #pragma unroll
        for (int ks2 = 0; ks2 < 4; ks2++) {
            bf16x8 hf[4];
            #pragma unroll
            for (int mt = 0; mt < 4; mt++)
                hf[mt] = *(const bf16x8*)&Hs[(mt * 16 + ln) * 136 + ks2 * 32 + quad * 8];
            #pragma unroll
            for (int nt = 0; nt < 4; nt++) {
                #pragma unroll
                for (int mt = 0; mt < 4; mt++)
                    acc[mt][nt] = __builtin_amdgcn_mfma_f32_16x16x32_bf16(hf[mt], w2f[ks2][nt], acc[mt][nt], 0, 0, 0);
            }
        }
        // no trailing barrier: next chunk writes the other H buffer
    }

    // epilogue: lane owns channel gn, 4 consecutive positions -> float4 NCHW store
    const int b = bm / 49;
    for (int nt = 0; nt < 4; nt++) {
        int gn = wn64 + nt * 16 + ln;
        float bs = b2[gn], g2 = g2v[gn];
        for (int mt = 0; mt < 4; mt++) {
            int gm0 = bm * 64 + mt * 16 + quad * 4;
            int hw0 = gm0 - b * 3136;
            f32x4 res;
            for (int r = 0; r < 4; r++)
                res[r] = bf2f(x2[(size_t)(gm0 + r) * 256 + gn]) + g2 * (acc[mt][nt][r] + bs);
            *(f32x4*)(outT + (size_t)(b * 256 + gn) * 3136 + hw0) = res;
        }
    }
}

// ---------------- K_attn: halo attention + LayerScale residual ----------------
__global__ __launch_bounds__(256) void k_attn(
    const u16* __restrict__ qkv, const float* __restrict__ bias,
    const u16* __restrict__ xh, const float* __restrict__ gamma1,
    u16* __restrict__ x2) {
    __shared__ __align__(16) u16 Kl[208 * 40];
    __shared__ __align__(16) u16 Vt[32 * 232];
    __shared__ __align__(16) u16 Pl[4][16 * 232];

    const int t = threadIdx.x;
    const int blk = blockIdx.x, head = blockIdx.y, b = blockIdx.z;
    const int bh = blk / 7, bw = blk - bh * 7;
    const int wave = t >> 6, lane = t & 63;
    const int ln = lane & 15, quad = lane >> 4;

    {
        int4 z = {0, 0, 0, 0};
        for (int i = t; i < (32 * 232) / 8; i += 256) ((int4*)Vt)[i] = z;
        for (int i = t; i < (4 * 16 * 232) / 8; i += 256) ((int4*)&Pl[0][0])[i] = z;
    }
    __syncthreads();

    for (int cid = t; cid < 208 * 8; cid += 256) {
        int pos = cid >> 3, part = cid & 7;
        int i = pos / 14, j = pos - i * 14;
        int gh = bh * 8 - 3 + i, gw = bw * 8 - 3 + j;
        bool valid = (pos < 196) && ((unsigned)gh < 56u) && ((unsigned)gw < 56u);
        int d0 = (part & 3) * 8;
        int4 v = {0, 0, 0, 0};
        if (valid) {
            size_t p = (size_t)(b * 56 + gh) * 56 + gw;
            v = *(const int4*)(qkv + p * 768 + 256 + head * 64 + ((part & 4) ? 32 : 0) + d0);
        }
        if (!(part & 4)) {
            *(int4*)&Kl[pos * 40 + d0] = v;
        } else {
            alignas(16) u16 tmp[8];
            *(int4*)tmp = v;
            for (int jj = 0; jj < 8; jj++) Vt[(d0 + jj) * 232 + pos] = tmp[jj];
        }
    }
    __syncthreads();

    const int qrow = wave * 16 + ln;
    const int qh = bh * 8 + (qrow >> 3), qw = bw * 8 + (qrow & 7);
    const size_t qp = (size_t)(b * 56 + qh) * 56 + qw;
    bf16x8 qf = *(const bf16x8*)(qkv + qp * 768 + head * 32 + quad * 8);

    f32x4 vzero = {0.f, 0.f, 0.f, 0.f};
    float sv[13][4];
    float mx[4] = {-1e30f, -1e30f, -1e30f, -1e30f};
    const float scale = 0.17677669529663687f;
    for (int nt = 0; nt < 13; nt++) {
        bf16x8 kf = *(const bf16x8*)&Kl[(nt * 16 + ln) * 40 + quad * 8];
        f32x4 s = __builtin_amdgcn_mfma_f32_16x16x32_bf16(qf, kf, vzero, 0, 0, 0);
        int kk = nt * 16 + ln;
        bool kvalid = kk < 196;
        for (int r = 0; r < 4; r++) {
            int qq = wave * 16 + quad * 4 + r;
            float val = kvalid ? (s[r] * scale + bias[(size_t)(head * 64 + qq) * 196 + kk]) : -1e30f;
            sv[nt][r] = val;
            mx[r] = fmaxf(mx[r], val);
        }
    }
    for (int o = 1; o < 16; o <<= 1)
        for (int r = 0; r < 4; r++) mx[r] = fmaxf(mx[r], __shfl_xor(mx[r], o, 16));
    float sum[4] = {0.f, 0.f, 0.f, 0.f};
    for (int nt = 0; nt < 13; nt++)
        for (int r = 0; r < 4; r++) {
            float e = __expf(sv[nt][r] - mx[r]);
            sv[nt][r] = e;
            sum[r] += e;
        }
    for (int o = 1; o < 16; o <<= 1)
        for (int r = 0; r < 4; r++) sum[r] += __shfl_xor(sum[r], o, 16);
    float rinv[4];
    for (int r = 0; r < 4; r++) rinv[r] = 1.f / sum[r];

    u16* plw = &Pl[wave][0];
    for (int nt = 0; nt < 13; nt++)
        for (int r = 0; r < 4; r++)
            plw[(quad * 4 + r) * 232 + nt * 16 + ln] = f2bf(sv[nt][r]);
    __syncthreads();

    f32x4 o_acc[2];
    o_acc[0] = vzero; o_acc[1] = vzero;
    for (int kc = 0; kc < 7; kc++) {
        bf16x8 pf = *(const bf16x8*)&plw[ln * 232 + kc * 32 + quad * 8];
        for (int n2 = 0; n2 < 2; n2++) {
            bf16x8 vf = *(const bf16x8*)&Vt[(n2 * 16 + ln) * 232 + kc * 32 + quad * 8];
            o_acc[n2] = __builtin_amdgcn_mfma_f32_16x16x32_bf16(pf, vf, o_acc[n2], 0, 0, 0);
        }
    }

    for (int n2 = 0; n2 < 2; n2++) {
        int c = head * 32 + n2 * 16 + ln;
        float g1 = gamma1[c];
        for (int r = 0; r < 4; r++) {
            int q = wave * 16 + quad * 4 + r;
            int hh = bh * 8 + (q >> 3), ww = bw * 8 + (q & 7);
            size_t p = (size_t)(b * 56 + hh) * 56 + ww;
            float a = o_acc[n2][r] * rinv[r];
            x2[p * 256 + c] = f2bf(bf2f(xh[p * 256 + c]) + g1 * a);
        }
    }
}

extern "C" void kernel_launch(void* const* d_in, const int* in_sizes, int n_in,
                              void* d_out, int out_size, void* d_ws, size_t ws_size,
                              hipStream_t stream) {
    const float* x      = (const float*)d_in[0];
    const float* ln1_g  = (const float*)d_in[1];
    const float* ln1_b  = (const float*)d_in[2];
    const float* wq     = (const float*)d_in[3];
    const float* bq     = (const float*)d_in[4];
    const float* wkv    = (const float*)d_in[5];
    const float* bkv    = (const float*)d_in[6];
    const float* bias   = (const float*)d_in[7];
    const float* gamma1 = (const float*)d_in[8];
    const float* ln2_g  = (const float*)d_in[9];
    const float* ln2_b  = (const float*)d_in[10];
    const float* w1     = (const float*)d_in[11];
    const float* b1     = (const float*)d_in[12];
    const float* w2     = (const float*)d_in[13];
    const float* b2     = (const float*)d_in[14];
    const float* gamma2 = (const float*)d_in[15];

    char* ws = (char*)d_ws;
    u16* qkv   = (u16*)ws;                      // 77,070,336 B
    u16* xh    = (u16*)(ws + 77070336);         // 25,690,112 B  (also reused as xn2)
    u16* x2    = (u16*)(ws + 102760448);        // 25,690,112 B  (also reused as xn1)
    u16* wqkvb = (u16*)(ws + 128450560);        // 393,216 B
    u16* w1p   = (u16*)(ws + 128843776);        // 524,288 B
    u16* w2p   = (u16*)(ws + 129368064);        // 524,288 B
    u16* xn1   = x2;   // LN1 output; dead before k_attn writes x2
    u16* xn2   = xh;   // LN2 output; xh dead after k_attn

    k_prep<<<dim3(448), 256, 0, stream>>>(wq, wkv, w1, w2, wqkvb, w1p, w2p);
    k_transpose<<<dim3(49, 4, 16), 256, 0, stream>>>(x, xh);
    k_ln<<<dim3(12544), 256, 0, stream>>>(xh, xn1, ln1_g, ln1_b);
    k_qkv<<<dim3(2352), 256, 0, stream>>>(xn1, wqkvb, bq, bkv, qkv);
    k_attn<<<dim3(49, 8, 16), 256, 0, stream>>>(qkv, bias, xh, gamma1, x2);
    k_ln<<<dim3(12544), 256, 0, stream>>>(x2, xn2, ln2_g, ln2_b);
    k_mlp<<<dim3(784), 256, 0, stream>>>(xn2, x2, w1p, b1, w2p, b2, gamma2, (float*)d_out);
}

// Round 3
// 335.366 us; speedup vs baseline: 1.4254x; 1.1721x over previous
//
#include <hip/hip_runtime.h>
#include <hip/hip_bf16.h>
#include <math.h>

typedef unsigned short u16;
typedef float f32x4 __attribute__((ext_vector_type(4)));
typedef __bf16 bf16x8 __attribute__((ext_vector_type(8)));

__device__ __forceinline__ float bf2f(u16 u) {
    union { float f; unsigned int i; } v; v.i = ((unsigned int)u) << 16; return v.f;
}
__device__ __forceinline__ u16 f2bf(float f) {
    union { float f; unsigned int i; } v; v.f = f;
    unsigned int x = v.i;
    return (u16)((x + 0x7FFFu + ((x >> 16) & 1u)) >> 16);
}
__device__ __forceinline__ unsigned int cvt_pk_bf16(float lo, float hi) {
    unsigned int r;
    asm("v_cvt_pk_bf16_f32 %0, %1, %2" : "=v"(r) : "v"(lo), "v"(hi));
    return r;
}

// ---------------- K0: one-time weight conversion + fragment reordering ----------------
// bid [0,192): wqkvb[768][256] row-major bf16. wq rows (first 65536 elems) pre-scaled by dh^-0.5.
// bid [192,320): w1p fragment order (up B-frag)
// bid [320,448): w2p fragment order (down B-frag)
__global__ __launch_bounds__(256) void k_prep(const float* __restrict__ wq, const float* __restrict__ wkv,
                                              const float* __restrict__ w1, const float* __restrict__ w2,
                                              u16* __restrict__ wqkvb, u16* __restrict__ w1p, u16* __restrict__ w2p) {
    const int bid = blockIdx.x, t = threadIdx.x;
    if (bid < 192) {
        int e = (bid * 256 + t) * 4;
        const float* src = (e < 65536) ? (wq + e) : (wkv + (e - 65536));
        float sc = (e < 65536) ? 0.17677669529663687f : 1.f;  // fold attn scale into Q weights
        float4 v = *(const float4*)src;
        ushort4 o;
        o.x = f2bf(v.x * sc); o.y = f2bf(v.y * sc); o.z = f2bf(v.z * sc); o.w = f2bf(v.w * sc);
        *(ushort4*)(wqkvb + e) = o;
    } else if (bid < 320) {
        int tid = (bid - 192) * 256 + t;
        int kc = tid >> 11, rem = tid & 2047;
        int wave = rem >> 9, rem2 = rem & 511;
        int ks = rem2 >> 6, lane = rem2 & 63;
        int ln = lane & 15, quad = lane >> 4;
        const float* src = w1 + (size_t)(kc * 64 + wave * 16 + ln) * 256 + ks * 32 + quad * 8;
        float4 v0 = *(const float4*)src;
        float4 v1 = *(const float4*)(src + 4);
        alignas(16) u16 tmp[8];
        tmp[0] = f2bf(v0.x); tmp[1] = f2bf(v0.y); tmp[2] = f2bf(v0.z); tmp[3] = f2bf(v0.w);
        tmp[4] = f2bf(v1.x); tmp[5] = f2bf(v1.y); tmp[6] = f2bf(v1.z); tmp[7] = f2bf(v1.w);
        *(int4*)(w1p + (size_t)tid * 8) = *(int4*)tmp;
    } else {
        int tid = (bid - 320) * 256 + t;
        int kc = tid >> 11, rem = tid & 2047;
        int wave = rem >> 9, rem2 = rem & 511;
        int ks2 = rem2 >> 8, rem3 = rem2 & 255;
        int nt = rem3 >> 6, lane = rem3 & 63;
        int ln = lane & 15, quad = lane >> 4;
        const float* src = w2 + (size_t)(wave * 64 + nt * 16 + ln) * 1024 + kc * 64 + ks2 * 32 + quad * 8;
        float4 v0 = *(const float4*)src;
        float4 v1 = *(const float4*)(src + 4);
        alignas(16) u16 tmp[8];
        tmp[0] = f2bf(v0.x); tmp[1] = f2bf(v0.y); tmp[2] = f2bf(v0.z); tmp[3] = f2bf(v0.w);
        tmp[4] = f2bf(v1.x); tmp[5] = f2bf(v1.y); tmp[6] = f2bf(v1.z); tmp[7] = f2bf(v1.w);
        *(int4*)(w2p + (size_t)tid * 8) = *(int4*)tmp;
    }
}

// ---------------- K1: NCHW f32 -> NHWC bf16 transpose ----------------
__global__ __launch_bounds__(256) void k_transpose(const float* __restrict__ x, u16* __restrict__ xh) {
    __shared__ __align__(16) u16 tile[64][72];
    const int t = threadIdx.x;
    const int hw0 = blockIdx.x * 64;
    const int c0  = blockIdx.y * 64;
    const int b   = blockIdx.z;
    const int cl = t >> 2, wl = (t & 3) * 16;
    {
        int c = c0 + cl;
        const float* src = x + (size_t)(b * 256 + c) * 3136 + hw0 + wl;
        for (int q = 0; q < 4; q++) {
            float4 v = *(const float4*)(src + q * 4);
            u16* dst = &tile[cl][wl + q * 4];
            dst[0] = f2bf(v.x); dst[1] = f2bf(v.y); dst[2] = f2bf(v.z); dst[3] = f2bf(v.w);
        }
    }
    __syncthreads();
    const int hl = t >> 3, cl2 = (t & 7) * 8;
    for (int i = 0; i < 2; i++) {
        int hw = hl + i * 32;
        alignas(16) u16 tmp[8];
        for (int j = 0; j < 8; j++) tmp[j] = tile[cl2 + j][hw];
        u16* dst = xh + (size_t)(b * 3136 + hw0 + hw) * 256 + c0 + cl2;
        *(int4*)dst = *(int4*)tmp;
    }
}

// ---------------- K_ln: full LayerNorm, bf16 in -> bf16 out (materialized) ----------------
__global__ __launch_bounds__(256) void k_ln(const u16* __restrict__ in, u16* __restrict__ out,
                                            const float* __restrict__ g, const float* __restrict__ bta) {
    const int wave = threadIdx.x >> 6, lane = threadIdx.x & 63;
    const int p = blockIdx.x * 4 + wave;
    ushort4 v = *(const ushort4*)(in + (size_t)p * 256 + lane * 4);
    float f0 = bf2f(v.x), f1 = bf2f(v.y), f2 = bf2f(v.z), f3 = bf2f(v.w);
    float s = f0 + f1 + f2 + f3;
    float sq = f0 * f0 + f1 * f1 + f2 * f2 + f3 * f3;
    for (int o = 32; o >= 1; o >>= 1) { s += __shfl_xor(s, o, 64); sq += __shfl_xor(sq, o, 64); }
    float m = s * (1.f / 256.f);
    float var = sq * (1.f / 256.f) - m * m;
    float inv = rsqrtf(var + 1e-5f);
    float4 gv = *(const float4*)(g + lane * 4);
    float4 bv = *(const float4*)(bta + lane * 4);
    ushort4 o4;
    o4.x = f2bf((f0 - m) * inv * gv.x + bv.x);
    o4.y = f2bf((f1 - m) * inv * gv.y + bv.y);
    o4.z = f2bf((f2 - m) * inv * gv.z + bv.z);
    o4.w = f2bf((f3 - m) * inv * gv.w + bv.w);
    *(ushort4*)(out + (size_t)p * 256 + lane * 4) = o4;
}

// ---------------- K_qkv: qkv = xn @ wqkvb^T + [bq;bkv]  (pure-copy staging) ----------------
// grid 2352 1D, XCD-swizzled. Q output (cols 0..255) pre-scaled by dh^-0.5 (weights + bias).
__global__ __launch_bounds__(256) void k_qkv(
    const u16* __restrict__ xn, const u16* __restrict__ Bw,
    const float* __restrict__ bq, const float* __restrict__ bkv,
    u16* __restrict__ out) {
    __shared__ __align__(16) u16 smem[17408];
    u16* As = smem;          // 128*32
    u16* Bs = smem + 4096;   // 128*32

    const int g = blockIdx.x;
    const int xcd = g & 7, idx = g >> 3;
    const int bm = xcd * 49 + idx / 6, bn = idx % 6;

    const int t = threadIdx.x;
    const int wave = t >> 6, lane = t & 63;
    const int wm = (wave >> 1) * 64, wn = (wave & 1) * 64;
    const int ln = lane & 15, quad = lane >> 4;

    f32x4 vzero = {0.f, 0.f, 0.f, 0.f};
    f32x4 acc[4][4];
    for (int i = 0; i < 4; i++) for (int j = 0; j < 4; j++) acc[i][j] = vzero;

    const int srow = t >> 2;
    const int scol = (t & 3) * 8;

    for (int k0 = 0; k0 < 256; k0 += 32) {
        for (int i = 0; i < 2; i++) {
            int r = srow + i * 64;
            *(int4*)&As[r * 32 + scol] = *(const int4*)(xn + (size_t)(bm * 128 + r) * 256 + k0 + scol);
            *(int4*)&Bs[r * 32 + scol] = *(const int4*)(Bw + (size_t)(bn * 128 + r) * 256 + k0 + scol);
        }
        __syncthreads();
        bf16x8 af[4], bfr[4];
        for (int mt = 0; mt < 4; mt++) af[mt] = *(const bf16x8*)&As[(wm + mt * 16 + ln) * 32 + quad * 8];
        for (int nt = 0; nt < 4; nt++) bfr[nt] = *(const bf16x8*)&Bs[(wn + nt * 16 + ln) * 32 + quad * 8];
        for (int mt = 0; mt < 4; mt++)
            for (int nt = 0; nt < 4; nt++)   // swapped: lane owns row (m), 4 consecutive cols
                acc[mt][nt] = __builtin_amdgcn_mfma_f32_16x16x32_bf16(bfr[nt], af[mt], acc[mt][nt], 0, 0, 0);
        __syncthreads();
    }

    u16* Cs = smem;  // [128][136]
    for (int nt = 0; nt < 4; nt++) {
        int gn0 = bn * 128 + wn + nt * 16 + quad * 4;
        f32x4 bv;
        if (gn0 < 256) {
            f32x4 tq = *(const f32x4*)(bq + gn0);
            bv = tq * 0.17677669529663687f;   // pre-scale Q bias
        } else {
            bv = *(const f32x4*)(bkv + gn0 - 256);
        }
        for (int mt = 0; mt < 4; mt++) {
            ushort4 pk;
            pk.x = f2bf(acc[mt][nt][0] + bv[0]);
            pk.y = f2bf(acc[mt][nt][1] + bv[1]);
            pk.z = f2bf(acc[mt][nt][2] + bv[2]);
            pk.w = f2bf(acc[mt][nt][3] + bv[3]);
            *(ushort4*)&Cs[(wm + mt * 16 + ln) * 136 + wn + nt * 16 + quad * 4] = pk;
        }
    }
    __syncthreads();
    const int row = t >> 4, col = (t & 15) * 8;
    for (int pass = 0; pass < 8; pass++) {
        int rr = pass * 16 + row;
        int4 v = *(int4*)&Cs[rr * 136 + col];
        *(int4*)(out + (size_t)(bm * 128 + rr) * 768 + bn * 128 + col) = v;
    }
}

// ---------------- K_mlp: fused out = x2 + g2*(gelu(xn@w1^T+b1)@w2^T+b2), NCHW f32 ----------------
__global__ __launch_bounds__(256) void k_mlp(
    const u16* __restrict__ xn, const u16* __restrict__ x2,
    const u16* __restrict__ w1p, const float* __restrict__ b1,
    const u16* __restrict__ w2p, const float* __restrict__ b2,
    const float* __restrict__ g2v, float* __restrict__ outT) {
    __shared__ __align__(16) u16 smem[16896 + 2 * 8704];  // As 64x264, Hs[2] 64x136
    u16* As = smem;

    const int g = blockIdx.x;
    const int bm = (g & 7) * 98 + (g >> 3);

    const int t = threadIdx.x;
    const int wave = t >> 6, lane = t & 63;
    const int ln = lane & 15, quad = lane >> 4;
    const int wn64 = wave * 64;
    const int wq4 = (wave >> 1) * 4 + (wave & 1) * 2;   // = wave*2 (w1 group base)

    f32x4 vzero = {0.f, 0.f, 0.f, 0.f};
    f32x4 acc[4][4];  // [mt][nt]: n = wn64+nt*16+ln, m = mt*16+quad*4+r
    for (int i = 0; i < 4; i++) for (int j = 0; j < 4; j++) acc[i][j] = vzero;

    // stage A tile (pure copy, already LN'd)
    {
        const int srow = t >> 2, scb = (t & 3) * 8;
        for (int c = 0; c < 8; c++) {
            int col = scb + c * 32;
            *(int4*)&As[srow * 264 + col] = *(const int4*)(xn + (size_t)(bm * 64 + srow) * 256 + col);
        }
    }
    __syncthreads();

    for (int kc = 0; kc < 8; kc++) {
        u16* Hs = smem + 16896 + (kc & 1) * 8704;  // double-buffered H chunk
        // ---- batch-prefetch all 16 w1 fragments for this chunk ----
        bf16x8 w1f[2][8];
        {
            const u16* w1b = w1p + (size_t)(kc * 8 + wq4) * 4096 + lane * 8;
            #pragma unroll
            for (int nt = 0; nt < 2; nt++)
                #pragma unroll
                for (int ks = 0; ks < 8; ks++)
                    w1f[nt][ks] = *(const bf16x8*)(w1b + nt * 4096 + ks * 512);
        }
        // ---- up: H chunk 64m x 128n; this wave computes 64m x 32n. ----
        f32x4 up[4][2];
        #pragma unroll
        for (int i = 0; i < 4; i++) { up[i][0] = vzero; up[i][1] = vzero; }
        #pragma unroll
        for (int ks = 0; ks < 8; ks++) {
            #pragma unroll
            for (int mt = 0; mt < 4; mt++) {
                bf16x8 af = *(const bf16x8*)&As[(mt * 16 + ln) * 264 + ks * 32 + quad * 8];
                up[mt][0] = __builtin_amdgcn_mfma_f32_16x16x32_bf16(w1f[0][ks], af, up[mt][0], 0, 0, 0);
                up[mt][1] = __builtin_amdgcn_mfma_f32_16x16x32_bf16(w1f[1][ks], af, up[mt][1], 0, 0, 0);
            }
        }
        // ---- batch-prefetch all 16 w2 fragments (issue before barrier; used after) ----
        bf16x8 w2f[4][4];
        #pragma unroll
        for (int ks2 = 0; ks2 < 4; ks2++) {
            const u16* w2b = w2p + (size_t)((((kc * 2 + (ks2 >> 1)) * 4 + wave) * 2 + (ks2 & 1)) * 4) * 512 + lane * 8;
            #pragma unroll
            for (int nt = 0; nt < 4; nt++)
                w2f[ks2][nt] = *(const bf16x8*)(w2b + nt * 512);
        }
        // ---- gelu (sigmoid form; downstream scaled by gamma2~1e-6) -> packed b64 writes ----
        #pragma unroll
        for (int nt = 0; nt < 2; nt++) {
            float4 bv = *(const float4*)(b1 + kc * 128 + wave * 32 + nt * 16 + quad * 4);
            #pragma unroll
            for (int mt = 0; mt < 4; mt++) {
                float v0 = up[mt][nt][0] + bv.x;
                float v1 = up[mt][nt][1] + bv.y;
                float v2 = up[mt][nt][2] + bv.z;
                float v3 = up[mt][nt][3] + bv.w;
                ushort4 pk;
                pk.x = f2bf(v0 * (1.f / (1.f + __expf(-1.702f * v0))));
                pk.y = f2bf(v1 * (1.f / (1.f + __expf(-1.702f * v1))));
                pk.z = f2bf(v2 * (1.f / (1.f + __expf(-1.702f * v2))));
                pk.w = f2bf(v3 * (1.f / (1.f + __expf(-1.702f * v3))));
                *(ushort4*)&Hs[(mt * 16 + ln) * 136 + wave * 32 + nt * 16 + quad * 4] = pk;
            }
        }
        __syncthreads();
        // ---- down: acc += H(64x128) @ W2chunk^T; K=128 in 4 slices of 32. ----
        #pragma unroll
        for (int ks2 = 0; ks2 < 4; ks2++) {
            bf16x8 hf[4];
            #pragma unroll
            for (int mt = 0; mt < 4; mt++)
                hf[mt] = *(const bf16x8*)&Hs[(mt * 16 + ln) * 136 + ks2 * 32 + quad * 8];
            #pragma unroll
            for (int nt = 0; nt < 4; nt++) {
                #pragma unroll
                for (int mt = 0; mt < 4; mt++)
                    acc[mt][nt] = __builtin_amdgcn_mfma_f32_16x16x32_bf16(hf[mt], w2f[ks2][nt], acc[mt][nt], 0, 0, 0);
            }
        }
        // no trailing barrier: next chunk writes the other H buffer
    }

    // epilogue: lane owns channel gn, 4 consecutive positions -> float4 NCHW store
    const int b = bm / 49;
    for (int nt = 0; nt < 4; nt++) {
        int gn = wn64 + nt * 16 + ln;
        float bs = b2[gn], g2 = g2v[gn];
        for (int mt = 0; mt < 4; mt++) {
            int gm0 = bm * 64 + mt * 16 + quad * 4;
            int hw0 = gm0 - b * 3136;
            f32x4 res;
            for (int r = 0; r < 4; r++)
                res[r] = bf2f(x2[(size_t)(gm0 + r) * 256 + gn]) + g2 * (acc[mt][nt][r] + bs);
            *(f32x4*)(outT + (size_t)(b * 256 + gn) * 3136 + hw0) = res;
        }
    }
}

// ---------------- K_attn: halo attention + LayerScale residual ----------------
// v4: swapped QK^T (mfma(kf,qf)) -> lane owns a full softmax row (q=ln) with
//     k = nt*16 + quad*4 + r. P never touches LDS: PV uses a permuted k-slot
//     mapping (slot j<4 ~ k=32kc+4quad+j, slot j>=4 ~ +16) shared by the P and
//     V fragments (MFMA contraction is invariant under a common k permutation),
//     so the P fragment is pure register repacking (cvt_pk_bf16 pairs) and V is
//     read as two b64 per fragment. Bias rides in as the MFMA C operand
//     (float4 loads; Q pre-scaled by dh^-0.5 in k_prep/k_qkv).
//     Pl buffer (29.7 KB) + 2 barriers + zero-init eliminated.
//     LDS 31.7 KB -> 4 blocks/CU (VGPR-capped). Vt stride 236: d0-scatter write
//     conflicts 8-way -> 2-way (8*118 = 944 = 16 mod 32).
__global__ __launch_bounds__(256, 4) void k_attn(
    const u16* __restrict__ qkv, const float* __restrict__ bias,
    const u16* __restrict__ xh, const float* __restrict__ gamma1,
    u16* __restrict__ x2) {
    __shared__ __align__(16) u16 Kl[208 * 40];
    __shared__ __align__(16) u16 Vt[32 * 236];

    const int t = threadIdx.x;
    const int blk = blockIdx.x, head = blockIdx.y, b = blockIdx.z;
    const int bh = blk / 7, bw = blk - bh * 7;
    const int wave = t >> 6, lane = t & 63;
    const int ln = lane & 15, quad = lane >> 4;

    // stage K (row-major) + V (transposed scatter); invalid/halo-OOB -> zeros.
    for (int cid = t; cid < 208 * 8; cid += 256) {
        int pos = cid >> 3, part = cid & 7;
        int i = pos / 14, j = pos - i * 14;
        int gh = bh * 8 - 3 + i, gw = bw * 8 - 3 + j;
        bool valid = (pos < 196) && ((unsigned)gh < 56u) && ((unsigned)gw < 56u);
        int d0 = (part & 3) * 8;
        int4 v = {0, 0, 0, 0};
        if (valid) {
            size_t p = (size_t)(b * 56 + gh) * 56 + gw;
            v = *(const int4*)(qkv + p * 768 + 256 + head * 64 + ((part & 4) ? 32 : 0) + d0);
        }
        if (!(part & 4)) {
            *(int4*)&Kl[pos * 40 + d0] = v;
        } else {
            alignas(16) u16 tmp[8];
            *(int4*)tmp = v;
            for (int jj = 0; jj < 8; jj++) Vt[(d0 + jj) * 236 + pos] = tmp[jj];
        }
    }
    __syncthreads();

    const int qrow = wave * 16 + ln;   // this lane's q row (= softmax row)
    const int qh = bh * 8 + (qrow >> 3), qw = bw * 8 + (qrow & 7);
    const size_t qp = (size_t)(b * 56 + qh) * 56 + qw;
    bf16x8 qf = *(const bf16x8*)(qkv + qp * 768 + head * 32 + quad * 8);  // pre-scaled Q

    // QK^T swapped: s[nt][r] = S[q=qrow][k=nt*16+quad*4+r], bias as C-in.
    f32x4 s[13];
    const float* bp = bias + (size_t)(head * 64 + qrow) * 196 + quad * 4;
    #pragma unroll
    for (int nt = 0; nt < 13; nt++) {
        bf16x8 kf = *(const bf16x8*)&Kl[(nt * 16 + ln) * 40 + quad * 8];
        f32x4 c;
        if (nt < 12 || quad == 0) {
            c = *(const f32x4*)(bp + nt * 16);
        } else {
            c = (f32x4){-1e30f, -1e30f, -1e30f, -1e30f};  // k >= 196 masked
        }
        s[nt] = __builtin_amdgcn_mfma_f32_16x16x32_bf16(kf, qf, c, 0, 0, 0);
    }

    // row softmax: lane-local over 52 values + cross-quad combine (xor 16, 32)
    float mx = -1e30f;
    #pragma unroll
    for (int nt = 0; nt < 13; nt++)
        #pragma unroll
        for (int r = 0; r < 4; r++) mx = fmaxf(mx, s[nt][r]);
    mx = fmaxf(mx, __shfl_xor(mx, 16, 64));
    mx = fmaxf(mx, __shfl_xor(mx, 32, 64));
    float sum = 0.f;
    #pragma unroll
    for (int nt = 0; nt < 13; nt++)
        #pragma unroll
        for (int r = 0; r < 4; r++) {
            float e = __expf(s[nt][r] - mx);
            s[nt][r] = e;
            sum += e;
        }
    sum += __shfl_xor(sum, 16, 64);
    sum += __shfl_xor(sum, 32, 64);
    float rinv = 1.f / sum;

    // pack P rows to bf16 pairs (lane-local; k = nt*16 + quad*4 + r)
    unsigned int pk[13][2];
    #pragma unroll
    for (int nt = 0; nt < 13; nt++) {
        pk[nt][0] = cvt_pk_bf16(s[nt][0], s[nt][1]);
        pk[nt][1] = cvt_pk_bf16(s[nt][2], s[nt][3]);
    }

    // PV with common permuted k-slots: slot j<4 ~ k=32kc+4*quad+j; j>=4 ~ +16.
    f32x4 vzero = {0.f, 0.f, 0.f, 0.f};
    f32x4 o_acc[2];
    o_acc[0] = vzero; o_acc[1] = vzero;
    #pragma unroll
    for (int kc = 0; kc < 7; kc++) {
        union { int4 i4; bf16x8 v; } pu;
        pu.i4.x = pk[2 * kc][0];
        pu.i4.y = pk[2 * kc][1];
        pu.i4.z = (kc < 6) ? pk[2 * kc + 1][0] : 0;
        pu.i4.w = (kc < 6) ? pk[2 * kc + 1][1] : 0;
        #pragma unroll
        for (int n2 = 0; n2 < 2; n2++) {
            union { int4 i4; bf16x8 v; } vu;
            const u16* vb = &Vt[(n2 * 16 + ln) * 236 + kc * 32 + quad * 4];
            *(int2*)&vu.i4.x = *(const int2*)vb;
            if (kc < 6) {
                *(int2*)&vu.i4.z = *(const int2*)(vb + 16);
            } else {
                vu.i4.z = 0; vu.i4.w = 0;   // k 208..223: P slots are zero; avoid unwritten LDS
            }
            o_acc[n2] = __builtin_amdgcn_mfma_f32_16x16x32_bf16(pu.v, vu.v, o_acc[n2], 0, 0, 0);
        }
    }

    // rinv lives at lane (q, *): output row q = quad*4+r needs lane q's rinv
    float rr4[4];
    #pragma unroll
    for (int r = 0; r < 4; r++) rr4[r] = __shfl(rinv, quad * 4 + r, 16);

    #pragma unroll
    for (int n2 = 0; n2 < 2; n2++) {
        int c = head * 32 + n2 * 16 + ln;
        float g1 = gamma1[c];
        #pragma unroll
        for (int r = 0; r < 4; r++) {
            int q = wave * 16 + quad * 4 + r;
            int hh = bh * 8 + (q >> 3), ww = bw * 8 + (q & 7);
            size_t p = (size_t)(b * 56 + hh) * 56 + ww;
            float a = o_acc[n2][r] * rr4[r];
            x2[p * 256 + c] = f2bf(bf2f(xh[p * 256 + c]) + g1 * a);
        }
    }
}

extern "C" void kernel_launch(void* const* d_in, const int* in_sizes, int n_in,
                              void* d_out, int out_size, void* d_ws, size_t ws_size,
                              hipStream_t stream) {
    const float* x      = (const float*)d_in[0];
    const float* ln1_g  = (const float*)d_in[1];
    const float* ln1_b  = (const float*)d_in[2];
    const float* wq     = (const float*)d_in[3];
    const float* bq     = (const float*)d_in[4];
    const float* wkv    = (const float*)d_in[5];
    const float* bkv    = (const float*)d_in[6];
    const float* bias   = (const float*)d_in[7];
    const float* gamma1 = (const float*)d_in[8];
    const float* ln2_g  = (const float*)d_in[9];
    const float* ln2_b  = (const float*)d_in[10];
    const float* w1     = (const float*)d_in[11];
    const float* b1     = (const float*)d_in[12];
    const float* w2     = (const float*)d_in[13];
    const float* b2     = (const float*)d_in[14];
    const float* gamma2 = (const float*)d_in[15];

    char* ws = (char*)d_ws;
    u16* qkv   = (u16*)ws;                      // 77,070,336 B
    u16* xh    = (u16*)(ws + 77070336);         // 25,690,112 B  (also reused as xn2)
    u16* x2    = (u16*)(ws + 102760448);        // 25,690,112 B  (also reused as xn1)
    u16* wqkvb = (u16*)(ws + 128450560);        // 393,216 B
    u16* w1p   = (u16*)(ws + 128843776);        // 524,288 B
    u16* w2p   = (u16*)(ws + 129368064);        // 524,288 B
    u16* xn1   = x2;   // LN1 output; dead before k_attn writes x2
    u16* xn2   = xh;   // LN2 output; xh dead after k_attn

    k_prep<<<dim3(448), 256, 0, stream>>>(wq, wkv, w1, w2, wqkvb, w1p, w2p);
    k_transpose<<<dim3(49, 4, 16), 256, 0, stream>>>(x, xh);
    k_ln<<<dim3(12544), 256, 0, stream>>>(xh, xn1, ln1_g, ln1_b);
    k_qkv<<<dim3(2352), 256, 0, stream>>>(xn1, wqkvb, bq, bkv, qkv);
    k_attn<<<dim3(49, 8, 16), 256, 0, stream>>>(qkv, bias, xh, gamma1, x2);
    k_ln<<<dim3(12544), 256, 0, stream>>>(x2, xn2, ln2_g, ln2_b);
    k_mlp<<<dim3(784), 256, 0, stream>>>(xn2, x2, w1p, b1, w2p, b2, gamma2, (float*)d_out);
}